// Round 3
// baseline (266.134 us; speedup 1.0000x reference)
//
#include <hip/hip_runtime.h>
#include <hip/hip_bf16.h>

// Problem constants
#define B_ 4
#define L_ 4096
#define E_ 1024
#define H_ 16
#define D_ 64
#define N_ 64          // B*H heads
#define D2_ 128        // feature dim 2*D
#define EPS_ 1e-6f

#define CH_ 16             // phase1 L-chunks
#define LC_ 256            // rows per phase1 block
#define ANGSC (0.5f * 3.14159265358979f / (float)L_)

typedef short short8 __attribute__((ext_vector_type(8)));
typedef float f32x4 __attribute__((ext_vector_type(4)));
typedef unsigned int u32;
typedef unsigned short u16;

static __device__ __forceinline__ u16 bf16u(float x) {
  union { __hip_bfloat16 h; u16 s; } u;
  u.h = __float2bfloat16(x);
  return u.s;
}
static __device__ __forceinline__ u32 pack2bf(float a, float b) {
  return (u32)bf16u(a) | ((u32)bf16u(b) << 16);
}

// ---------------------------------------------------------------------------
// Phase 1 (MFMA, register-pipelined): partial kv[d][m] = sum_l k_[l][d]*v[l][m]
// ksum[d] = sum_l k_[l][d].  4 stages of 64 rows; stage s+1's k/v prefetched
// into registers while MFMA consumes stage s from LDS.
// ---------------------------------------------------------------------------
__global__ __launch_bounds__(256, 4) void phase1_mfma(
    const float* __restrict__ k, const float* __restrict__ v,
    const float* __restrict__ mask,
    float* __restrict__ part_kv, float* __restrict__ part_ks) {
  __shared__ __align__(16) u16 ka[D2_ * 72];   // [d][l] d<64 sin-part, >=64 cos
  __shared__ __align__(16) u16 vt[D_ * 72];    // [m][l]
  __shared__ float mm[LC_], ms[LC_], mc[LC_];  // mask, mask*sin, mask*cos

  const int bid = blockIdx.x;
  const int n = bid & 63, ch = bid >> 6;
  const int b = n >> 4, h = n & 15;
  const int t = threadIdx.x;
  const int wv = t >> 6, lane = t & 63;
  const int c_lo = lane & 15, lp = lane >> 4;
  const int c = wv * 16 + c_lo;

  // row-constant tables for the whole 256-row chunk (one-time)
  {
    const int gl = ch * LC_ + t;
    const float m = mask[b * L_ + gl];
    const float ang = (float)(gl + 1) * ANGSC;
    mm[t] = m;
    ms[t] = m * __sinf(ang);
    mc[t] = m * __cosf(ang);
  }

  const float* kbase = k + (size_t)(b * L_ + ch * LC_) * E_ + h * 64 + c;
  const float* vbase = v + (size_t)(b * L_ + ch * LC_) * E_ + h * 64 + c;

  // prefetch stage 0
  float pk0[8], pk1[8], pv0[8], pv1[8];
#pragma unroll
  for (int i = 0; i < 8; ++i) {
    const int l = 8 * i + 2 * lp;
    pk0[i] = kbase[(size_t)l * E_];
    pk1[i] = kbase[(size_t)(l + 1) * E_];
    pv0[i] = vbase[(size_t)l * E_];
    pv1[i] = vbase[(size_t)(l + 1) * E_];
  }

  f32x4 acc[2][4];
#pragma unroll
  for (int i = 0; i < 2; ++i)
#pragma unroll
    for (int j = 0; j < 4; ++j) acc[i][j] = (f32x4)0.f;
  float kss = 0.f, ksc = 0.f;

  for (int st = 0; st < 4; ++st) {
    __syncthreads();  // LDS free (prev stage's MFMA done); tables visible
    // pack prefetched regs -> LDS (bf16, transposed)
#pragma unroll
    for (int i = 0; i < 8; ++i) {
      const int l = 8 * i + 2 * lp, lg = st * 64 + l, li = 4 * i + lp;
      const float kr0 = fmaxf(pk0[i], 0.f), kr1 = fmaxf(pk1[i], 0.f);
      const float a0 = kr0 * ms[lg], a1 = kr1 * ms[lg + 1];
      const float c0 = kr0 * mc[lg], c1 = kr1 * mc[lg + 1];
      ((u32*)ka)[c * 36 + li] = pack2bf(a0, a1);
      ((u32*)ka)[(c + 64) * 36 + li] = pack2bf(c0, c1);
      ((u32*)vt)[c * 36 + li] = pack2bf(pv0[i] * mm[lg], pv1[i] * mm[lg + 1]);
      kss += a0 + a1;
      ksc += c0 + c1;
    }
    __syncthreads();
    // prefetch next stage while MFMA runs on this one
    if (st < 3) {
      const int lo = (st + 1) * 64;
#pragma unroll
      for (int i = 0; i < 8; ++i) {
        const int l = lo + 8 * i + 2 * lp;
        pk0[i] = kbase[(size_t)l * E_];
        pk1[i] = kbase[(size_t)(l + 1) * E_];
        pv0[i] = vbase[(size_t)l * E_];
        pv1[i] = vbase[(size_t)(l + 1) * E_];
      }
    }
    // MFMA: 2 K-steps of 32 l
#pragma unroll
    for (int kk = 0; kk < 2; ++kk) {
      const int colo = kk * 32 + lp * 8;
      short8 af[2], bfr[4];
#pragma unroll
      for (int dt = 0; dt < 2; ++dt)
        af[dt] = *(const short8*)&ka[(wv * 32 + dt * 16 + c_lo) * 72 + colo];
#pragma unroll
      for (int mt = 0; mt < 4; ++mt)
        bfr[mt] = *(const short8*)&vt[(mt * 16 + c_lo) * 72 + colo];
#pragma unroll
      for (int dt = 0; dt < 2; ++dt)
#pragma unroll
        for (int mt = 0; mt < 4; ++mt)
          acc[dt][mt] = __builtin_amdgcn_mfma_f32_16x16x32_bf16(
              af[dt], bfr[mt], acc[dt][mt], 0, 0, 0);
    }
  }

  // write partial kv (fp32). C layout: row(d)=quad*4+r, col(m)=lane&15
  const size_t pbase = (size_t)(ch * N_ + n) * (D2_ * D_);
#pragma unroll
  for (int dt = 0; dt < 2; ++dt) {
    const int d = wv * 32 + dt * 16 + lp * 4;
#pragma unroll
    for (int mt = 0; mt < 4; ++mt) {
      const int mcol = mt * 16 + c_lo;
#pragma unroll
      for (int r = 0; r < 4; ++r)
        part_kv[pbase + (size_t)(d + r) * D_ + mcol] = acc[dt][mt][r];
    }
  }
  kss += __shfl_xor(kss, 16); kss += __shfl_xor(kss, 32);
  ksc += __shfl_xor(ksc, 16); ksc += __shfl_xor(ksc, 32);
  if (lp == 0) {
    part_ks[(size_t)(ch * N_ + n) * D2_ + c] = kss;
    part_ks[(size_t)(ch * N_ + n) * D2_ + c + 64] = ksc;
  }
}

// ---------------------------------------------------------------------------
// Reduce: sum chunk partials; emit kvt[n][m][f] bf16 with INTERLEAVED feature
// order f = 2*d + (0=sin,1=cos), plus ksb[n][f] bf16 (same order).
// grid: 64 heads x 8 f-slices = 512 blocks.
// ---------------------------------------------------------------------------
__global__ __launch_bounds__(256) void reduce_t(
    const float* __restrict__ part_kv, const float* __restrict__ part_ks,
    u16* __restrict__ kvt, u16* __restrict__ ksb) {
  __shared__ float l0[8][65], l1[8][65];
  const int n = blockIdx.x & 63, fs = blockIdx.x >> 6;  // fs 0..7
  const int t = threadIdx.x;

#pragma unroll
  for (int p = 0; p < 4; ++p) {
    const int idx = t + 256 * p;  // 0..1023
    const int g = idx >> 9, dd = (idx >> 6) & 7, m = idx & 63;
    const int d = g * 64 + fs * 8 + dd;
    float s = 0.f;
#pragma unroll
    for (int cc = 0; cc < CH_; ++cc)
      s += part_kv[(size_t)(cc * N_ + n) * (D2_ * D_) + d * 64 + m];
    if (g == 0) l0[dd][m] = s; else l1[dd][m] = s;
  }
  if (fs == 0 && t < D2_) {
    float s = 0.f;
#pragma unroll
    for (int cc = 0; cc < CH_; ++cc)
      s += part_ks[(size_t)(cc * N_ + n) * D2_ + t];
    const int dloc = t & 63, half = t >> 6;
    ksb[n * D2_ + 2 * dloc + half] = bf16u(s);
  }
  __syncthreads();
  u32* kvt32 = (u32*)(kvt + (size_t)n * (D_ * D2_));
#pragma unroll
  for (int p = 0; p < 2; ++p) {
    const int idx = t + 256 * p;  // 0..511
    const int j = idx & 7, m = idx >> 3;
    kvt32[m * 64 + fs * 8 + j] = pack2bf(l0[j][m], l1[j][m]);
  }
}

// ---------------------------------------------------------------------------
// Phase 2 (MFMA, zero LDS): out[l][m] = z[l] * sum_f q_[l][f] * kvt[m][f]
// A-frag: one float4 of q per lane per K-step (f interleaved -> 4 consecutive
// q floats x {sin,cos}). B-frags straight from kvt (L1-resident, 16KB/head).
// z via extra B-tile = broadcast ksum row (cols 1..15 don't affect col 0).
// grid: 64 heads x 64 row-tiles; each wave independent (16 rows), no barriers.
// ---------------------------------------------------------------------------
__global__ __launch_bounds__(256, 4) void phase2_mfma(
    const float* __restrict__ q, const u16* __restrict__ kvt,
    const u16* __restrict__ ksb, float* __restrict__ out) {
  const int bid = blockIdx.x;
  const int n = bid & 63, lt = bid >> 6;
  const int b = n >> 4, h = n & 15;
  const int t = threadIdx.x;
  const int wv = t >> 6, lane = t & 63;
  const int c_lo = lane & 15, quad = lane >> 4;
  const int l = lt * 64 + wv * 16 + c_lo;  // this lane's A-row

  const float ang = (float)(l + 1) * ANGSC;
  const float sn = __sinf(ang), cs = __cosf(ang);

  const float* qrow = q + (size_t)(b * L_ + l) * E_ + h * 64;
  short8 af[4];
#pragma unroll
  for (int kk = 0; kk < 4; ++kk) {
    const float4 qv = *(const float4*)(qrow + kk * 16 + quad * 4);
    const float x = fmaxf(qv.x, 0.f), y = fmaxf(qv.y, 0.f);
    const float z2 = fmaxf(qv.z, 0.f), w = fmaxf(qv.w, 0.f);
    short8 a;
    a[0] = (short)bf16u(x * sn); a[1] = (short)bf16u(x * cs);
    a[2] = (short)bf16u(y * sn); a[3] = (short)bf16u(y * cs);
    a[4] = (short)bf16u(z2 * sn); a[5] = (short)bf16u(z2 * cs);
    a[6] = (short)bf16u(w * sn); a[7] = (short)bf16u(w * cs);
    af[kk] = a;
  }

  const u16* kvh = kvt + (size_t)n * (D_ * D2_);
  const u16* ksh = ksb + n * D2_;
  f32x4 acc[4], acc5 = (f32x4)0.f;
#pragma unroll
  for (int mt = 0; mt < 4; ++mt) acc[mt] = (f32x4)0.f;

#pragma unroll
  for (int kk = 0; kk < 4; ++kk) {
    const int fo = kk * 32 + quad * 8;
#pragma unroll
    for (int mt = 0; mt < 4; ++mt) {
      const short8 bfr = *(const short8*)&kvh[(mt * 16 + c_lo) * D2_ + fo];
      acc[mt] = __builtin_amdgcn_mfma_f32_16x16x32_bf16(af[kk], bfr, acc[mt], 0, 0, 0);
    }
    const short8 bks = *(const short8*)&ksh[fo];  // broadcast: all cols = ksum
    acc5 = __builtin_amdgcn_mfma_f32_16x16x32_bf16(af[kk], bks, acc5, 0, 0, 0);
  }

  // epilogue: z from acc5 col 0 (lane quad*16 holds row quad*4+r, col 0)
#pragma unroll
  for (int r = 0; r < 4; ++r) {
    const float den = __shfl(acc5[r], quad * 16);
    const float zz = 1.f / fmaxf(den, EPS_);
    const int gl = lt * 64 + wv * 16 + quad * 4 + r;
    float* ob = out + (size_t)n * (L_ * D_) + (size_t)gl * D_;
#pragma unroll
    for (int mt = 0; mt < 4; ++mt) ob[mt * 16 + c_lo] = acc[mt][r] * zz;
  }
}

// ---------------------------------------------------------------------------
extern "C" void kernel_launch(void* const* d_in, const int* in_sizes, int n_in,
                              void* d_out, int out_size, void* d_ws,
                              size_t ws_size, hipStream_t stream) {
  const float* q = (const float*)d_in[0];
  const float* k = (const float*)d_in[1];
  const float* v = (const float*)d_in[2];
  const float* mask = (const float*)d_in[3];
  float* out = (float*)d_out;

  float* part_kv = (float*)d_ws;                            // 16*64*8192 f32 = 32 MB
  float* part_ks = part_kv + (size_t)CH_ * N_ * D2_ * D_;   // 16*64*128 f32 = 512 KB
  u16* kvt = (u16*)(part_ks + (size_t)CH_ * N_ * D2_);      // 64*8192 bf16 = 1 MB
  u16* ksb = kvt + (size_t)N_ * D2_ * D_;                   // 64*128 bf16 = 16 KB

  phase1_mfma<<<dim3(CH_ * N_), dim3(256), 0, stream>>>(k, v, mask, part_kv, part_ks);
  reduce_t<<<dim3(8 * N_), dim3(256), 0, stream>>>(part_kv, part_ks, kvt, ksb);
  phase2_mfma<<<dim3(N_ * 64), dim3(256), 0, stream>>>(q, kvt, ksb, out);
}